// Round 6
// baseline (756.014 us; speedup 1.0000x reference)
//
#include <hip/hip_runtime.h>
#include <math.h>

#define NB 16        // batch
#define CH 256       // hidden
#define CND 512      // cond channels
#define NH 4
#define KC 64
#define TTT 2048
#define TSS 512

// ---------------------------------------------------------------------------
// Templated tiled GEMM: Yn[b] = Wn @ X[b] + bn   (n < NOUT)
// W: [M,K] row-major, X: [B,K,T], Y: [B,M,T]. Tile 64 x (16*TN), BK=32.
// ---------------------------------------------------------------------------
template <int TN, int NOUT>
__global__ __launch_bounds__(256) void gemm_v2(
    const float* __restrict__ W0, const float* __restrict__ b0,
    const float* __restrict__ W1, const float* __restrict__ b1,
    const float* __restrict__ X, float* __restrict__ Y0, float* __restrict__ Y1,
    int K, int T) {
  constexpr int TT = 16 * TN;
  constexpr int TQ = TT / 4;
  constexpr int PB = (32 * TQ) / 256;
  const int t0 = blockIdx.x * TT;
  const int m0 = blockIdx.y * 64;
  const int b  = blockIdx.z;
  const int tid = threadIdx.x;
  const int tx = tid & 15, ty = tid >> 4;

  __shared__ float As[NOUT][32][68];
  __shared__ float Bs[32][TT + 4];

  const float* Xb = X + (size_t)b * K * T;
  float acc[NOUT][4][TN];
#pragma unroll
  for (int n = 0; n < NOUT; ++n)
#pragma unroll
    for (int i = 0; i < 4; ++i)
#pragma unroll
      for (int u = 0; u < TN; ++u) acc[n][i][u] = 0.f;

  const int am = tid >> 2, akq = tid & 3;

  for (int k0 = 0; k0 < K; k0 += 32) {
#pragma unroll
    for (int n = 0; n < NOUT; ++n) {
      const float* Wn = (n == 0) ? W0 : W1;
      float4 a0 = *(const float4*)&Wn[(size_t)(m0 + am) * K + k0 + 4 * akq];
      float4 a1 = *(const float4*)&Wn[(size_t)(m0 + am) * K + k0 + 16 + 4 * akq];
      As[n][4 * akq + 0][am] = a0.x; As[n][4 * akq + 1][am] = a0.y;
      As[n][4 * akq + 2][am] = a0.z; As[n][4 * akq + 3][am] = a0.w;
      As[n][16 + 4 * akq + 0][am] = a1.x; As[n][16 + 4 * akq + 1][am] = a1.y;
      As[n][16 + 4 * akq + 2][am] = a1.z; As[n][16 + 4 * akq + 3][am] = a1.w;
    }
#pragma unroll
    for (int p = 0; p < PB; ++p) {
      int idx = tid + p * 256;
      int t4 = idx & (TQ - 1), k = idx / TQ;
      *(float4*)&Bs[k][4 * t4] = *(const float4*)&Xb[(size_t)(k0 + k) * T + t0 + 4 * t4];
    }
    __syncthreads();
#pragma unroll
    for (int kk = 0; kk < 32; ++kk) {
      float4 av[NOUT];
#pragma unroll
      for (int n = 0; n < NOUT; ++n) av[n] = *(const float4*)&As[n][kk][4 * ty];
      float4 bv[TN / 4];
#pragma unroll
      for (int g = 0; g < TN / 4; ++g) bv[g] = *(const float4*)&Bs[kk][4 * tx + 64 * g];
#pragma unroll
      for (int n = 0; n < NOUT; ++n) {
        const float a4[4] = {av[n].x, av[n].y, av[n].z, av[n].w};
#pragma unroll
        for (int i = 0; i < 4; ++i)
#pragma unroll
          for (int g = 0; g < TN / 4; ++g) {
            acc[n][i][4 * g + 0] += a4[i] * bv[g].x;
            acc[n][i][4 * g + 1] += a4[i] * bv[g].y;
            acc[n][i][4 * g + 2] += a4[i] * bv[g].z;
            acc[n][i][4 * g + 3] += a4[i] * bv[g].w;
          }
      }
    }
    __syncthreads();
  }
#pragma unroll
  for (int n = 0; n < NOUT; ++n) {
    float* Yn = (n == 0) ? Y0 : Y1;
    const float* bn = (n == 0) ? b0 : b1;
#pragma unroll
    for (int i = 0; i < 4; ++i) {
      int row = m0 + 4 * ty + i;
      float bi = bn[row];
#pragma unroll
      for (int g = 0; g < TN / 4; ++g) {
        float4 ov;
        ov.x = acc[n][i][4 * g + 0] + bi; ov.y = acc[n][i][4 * g + 1] + bi;
        ov.z = acc[n][i][4 * g + 2] + bi; ov.w = acc[n][i][4 * g + 3] + bi;
        *(float4*)&Yn[((size_t)b * 256 + row) * T + t0 + 4 * tx + 64 * g] = ov;
      }
    }
  }
}

// ---------------------------------------------------------------------------
// Bias folding: bk2 = wk@b_cond + bk; bv2 = wv@b_cond + bv; bf2 = w_film@bo + b_film
// ---------------------------------------------------------------------------
__global__ __launch_bounds__(256) void bias_fold(
    const float* __restrict__ wk, const float* __restrict__ bk,
    const float* __restrict__ wv, const float* __restrict__ bv,
    const float* __restrict__ bcond,
    const float* __restrict__ wfilm, const float* __restrict__ bo,
    const float* __restrict__ bfilm,
    float* __restrict__ bk2, float* __restrict__ bv2, float* __restrict__ bf2) {
  int g = blockIdx.x * 256 + threadIdx.x;
  if (g < 256) {
    float s = bk[g];
    for (int k = 0; k < 256; ++k) s += wk[g * 256 + k] * bcond[k];
    bk2[g] = s;
  } else if (g < 512) {
    int m = g - 256;
    float s = bv[m];
    for (int k = 0; k < 256; ++k) s += wv[m * 256 + k] * bcond[k];
    bv2[m] = s;
  } else if (g < 1024) {
    int m = g - 512;
    float s = bfilm[m];
    for (int k = 0; k < 256; ++k) s += wfilm[m * 256 + k] * bo[k];
    bf2[m] = s;
  }
}

// ---------------------------------------------------------------------------
// In-place RoPE for K (q-RoPE is fused into attention staging)
// ---------------------------------------------------------------------------
__global__ __launch_bounds__(256) void rope_kernel(float* buf, int T, int tlog2) {
  int idx = blockIdx.x * 256 + threadIdx.x;
  int t = idx & (T - 1);
  int r = idx >> tlog2;
  int j = r & 31; r >>= 5;
  int h = r & 3;
  int b = r >> 2;
  if (b >= NB) return;
  float invf = expf(-(float)j * 0.28782313662425572f);
  float ang = (float)t * invf;
  float cs = cosf(ang), sn = sinf(ang);
  size_t base = ((size_t)(b * CH + h * KC + j)) * T + t;
  float q1 = buf[base];
  float q2 = buf[base + (size_t)32 * T];
  buf[base] = q1 * cs - q2 * sn;
  buf[base + (size_t)32 * T] = q2 * cs + q1 * sn;
}

// ---------------------------------------------------------------------------
// Attention v5: 64q x 64s tile, 128-thread block (2 waves), 8x4 S-frag,
// 8x4 O-frag. LDS 48 KB -> 3 blocks/CU (6 waves, 3 barrier domains) —
// fixes v4's 1-wave/SIMD latency stall while keeping low LDS traffic:
// QK^T 1 billable b128 / 32 MACs; PV 4 billable b128 / 128 MACs (Q/E reads
// broadcast). Pad-free via 16B-block XOR swizzles (E: blk^row, V: blk^ch);
// K stride-64 unswizzled (row-uniform reads). K/E/O share one buffer.
// Rows: row = 4*ty + (r&3) + 32*(r>>2), ty in [0,8). Cols: 4*tx+u. O chans:
// ch = tx + 16*m.
// ---------------------------------------------------------------------------
__global__ __launch_bounds__(128, 2) void attn_v5(
    const float* __restrict__ qbuf, const float* __restrict__ kbuf,
    const float* __restrict__ vbuf, const float* __restrict__ cond_mask,
    float* __restrict__ obuf) {
  const int t0 = blockIdx.x * 64;
  const int h  = blockIdx.y;
  const int b  = blockIdx.z;
  const int tid = threadIdx.x;
  const int tx = tid & 15, ty = tid >> 4;      // ty in [0,8)

  __shared__ float Qs[64 * 64];   // [j*64 + t]        (reads row-uniform)
  __shared__ float KE[64 * 64];   // K: [j*64+s] | E: [row*64 + 4*((c/4)^(row&15)) + c%4] | O: swizzled [ch][t]
  __shared__ float Vs[64 * 64];   // [ch*64 + 4*((s/4)^(ch&15)) + s%4]

  // ---- stage Q with fused RoPE ----
  const float* qb = qbuf + ((size_t)(b * CH + h * KC)) * TTT + t0;
#pragma unroll
  for (int p = 0; p < 4; ++p) {
    int idx = tid + p * 128;            // 0..511
    int j = idx >> 4, t4 = idx & 15;    // j in 0..31
    float4 qa = *(const float4*)&qb[(size_t)j * TTT + 4 * t4];
    float4 qc = *(const float4*)&qb[(size_t)(j + 32) * TTT + 4 * t4];
    float invf = expf(-(float)j * 0.28782313662425572f);
    const float qav[4] = {qa.x, qa.y, qa.z, qa.w};
    const float qcv[4] = {qc.x, qc.y, qc.z, qc.w};
    float oa[4], oc[4];
#pragma unroll
    for (int e = 0; e < 4; ++e) {
      float ang = (float)(t0 + 4 * t4 + e) * invf;
      float cs = cosf(ang), sn = sinf(ang);
      oa[e] = qav[e] * cs - qcv[e] * sn;
      oc[e] = qcv[e] * cs + qav[e] * sn;
    }
    *(float4*)&Qs[j * 64 + 4 * t4]        = make_float4(oa[0], oa[1], oa[2], oa[3]);
    *(float4*)&Qs[(j + 32) * 64 + 4 * t4] = make_float4(oc[0], oc[1], oc[2], oc[3]);
  }

  float acc_o[8][4] = {};
  float dden[8] = {};

  const float* kb = kbuf + ((size_t)(b * CH + h * KC)) * TSS;
  const float* vb = vbuf + ((size_t)(b * CH + h * KC)) * TSS;
  const float* cm = cond_mask + (size_t)b * TSS;

  int rows[8];
#pragma unroll
  for (int r = 0; r < 8; ++r) rows[r] = 4 * ty + (r & 3) + 32 * (r >> 2);

  for (int s0 = 0; s0 < TSS; s0 += 64) {
    __syncthreads();   // (A) prior tile's E/V reads done
    // ---- stage K (stride 64) and V (swizzled) ----
#pragma unroll
    for (int p = 0; p < 8; ++p) {
      int idx = tid + p * 128;           // 0..1023
      int ch = idx >> 4, s4 = idx & 15;
      *(float4*)&KE[ch * 64 + 4 * s4] =
          *(const float4*)&kb[(size_t)ch * TSS + s0 + 4 * s4];
      *(float4*)&Vs[ch * 64 + 4 * (s4 ^ (ch & 15))] =
          *(const float4*)&vb[(size_t)ch * TSS + s0 + 4 * s4];
    }
    __syncthreads();   // (B) staging (and first-iter Q) visible

    // ---- S = Q K^T : 8x4 frag; per j: 2 b128 Q (broadcast) + 1 b128 K ----
    float acc_s[8][4];
#pragma unroll
    for (int r = 0; r < 8; ++r)
#pragma unroll
      for (int u = 0; u < 4; ++u) acc_s[r][u] = 0.f;
#pragma unroll 8
    for (int j = 0; j < 64; ++j) {
      float4 q0 = *(const float4*)&Qs[j * 64 + 4 * ty];
      float4 q1 = *(const float4*)&Qs[j * 64 + 32 + 4 * ty];
      float4 kv = *(const float4*)&KE[j * 64 + 4 * tx];
      const float qv[8] = {q0.x, q0.y, q0.z, q0.w, q1.x, q1.y, q1.z, q1.w};
      const float k4[4] = {kv.x, kv.y, kv.z, kv.w};
#pragma unroll
      for (int r = 0; r < 8; ++r)
#pragma unroll
        for (int u = 0; u < 4; ++u) acc_s[r][u] += qv[r] * k4[u];
    }
    __syncthreads();   // (C) K reads done; KE becomes E

    // ---- mask + exp + E write (swizzled: block tx ^ (row&15)) ----
    float mk[4];
#pragma unroll
    for (int u = 0; u < 4; ++u)
      mk[u] = (cm[s0 + 4 * tx + u] != 0.f) ? 1.f : 0.f;
#pragma unroll
    for (int r = 0; r < 8; ++r) {
      int row = rows[r];
      float e0 = __expf(acc_s[r][0] * 0.125f) * mk[0];
      float e1 = __expf(acc_s[r][1] * 0.125f) * mk[1];
      float e2 = __expf(acc_s[r][2] * 0.125f) * mk[2];
      float e3 = __expf(acc_s[r][3] * 0.125f) * mk[3];
      dden[r] += e0 + e1 + e2 + e3;
      *(float4*)&KE[row * 64 + 4 * (tx ^ (row & 15))] = make_float4(e0, e1, e2, e3);
    }
    __syncthreads();   // (D) E visible

    // ---- O += P V : per q4 (4 s): 8 b128 E (broadcast) + 4 b128 V ----
#pragma unroll 2
    for (int q4 = 0; q4 < 16; ++q4) {
      float4 ev[8], vv[4];
#pragma unroll
      for (int r = 0; r < 8; ++r) {
        int row = rows[r];
        ev[r] = *(const float4*)&KE[row * 64 + 4 * (q4 ^ (row & 15))];
      }
#pragma unroll
      for (int m = 0; m < 4; ++m) {
        int ch = tx + 16 * m;
        vv[m] = *(const float4*)&Vs[ch * 64 + 4 * (q4 ^ (ch & 15))];
      }
#pragma unroll
      for (int r = 0; r < 8; ++r)
#pragma unroll
        for (int m = 0; m < 4; ++m)
          acc_o[r][m] += ev[r].x * vv[m].x + ev[r].y * vv[m].y +
                         ev[r].z * vv[m].z + ev[r].w * vv[m].w;
    }
  }

  // ---- row denominators: butterfly over 16 tx lanes ----
  float rd[8];
#pragma unroll
  for (int r = 0; r < 8; ++r) {
    float d = dden[r];
#pragma unroll
    for (int off = 1; off < 16; off <<= 1) d += __shfl_xor(d, off, 16);
    rd[r] = 1.f / fmaxf(d, 1e-30f);
  }

  __syncthreads();   // last E reads done; reuse KE as swizzled O [ch][t]
  // O store swizzled: phys block = (t/4) ^ (ch&15); intra-block t%4 preserved
#pragma unroll
  for (int r = 0; r < 8; ++r) {
    int row = rows[r];
#pragma unroll
    for (int m = 0; m < 4; ++m) {
      int ch = tx + 16 * m;
      KE[ch * 64 + 4 * ((row >> 2) ^ (ch & 15)) + (row & 3)] = acc_o[r][m] * rd[r];
    }
  }
  __syncthreads();

  float* ob = obuf + ((size_t)(b * CH + h * KC)) * TTT + t0;
#pragma unroll
  for (int p = 0; p < 8; ++p) {
    int idx = tid + p * 128;           // 0..1023
    int ch = idx >> 4, t4 = idx & 15;
    *(float4*)&ob[(size_t)ch * TTT + 4 * t4] =
        *(const float4*)&KE[ch * 64 + 4 * (t4 ^ (ch & 15))];
  }
}

// ---------------------------------------------------------------------------
// Film: gb = wf2 @ ao + bf2; out = (x*gamma + beta) * x_mask
// wf2 = w_film@wo (precomputed), bf2 = w_film@bo + b_film (precomputed).
// ---------------------------------------------------------------------------
__global__ __launch_bounds__(256) void film_v2(
    const float* __restrict__ wf, const float* __restrict__ bfilm,
    const float* __restrict__ Yb, const float* __restrict__ X,
    const float* __restrict__ xmask, float* __restrict__ out) {
  const int t0 = blockIdx.x * 128;
  const int m0 = blockIdx.y * 64;
  const int b  = blockIdx.z;
  const int tid = threadIdx.x;
  const int tx = tid & 15, ty = tid >> 4;

  __shared__ float Ag[32][68];
  __shared__ float Ab[32][68];
  __shared__ float Bs[32][132];

  const float* Y = Yb + (size_t)b * CH * TTT;
  float accg[4][8], accb[4][8];
#pragma unroll
  for (int i = 0; i < 4; ++i)
#pragma unroll
    for (int u = 0; u < 8; ++u) { accg[i][u] = 0.f; accb[i][u] = 0.f; }

  const int am = tid >> 2, akq = tid & 3;

  for (int k0 = 0; k0 < 256; k0 += 32) {
    {
      float4 a0 = *(const float4*)&wf[(size_t)(m0 + am) * 256 + k0 + 4 * akq];
      float4 a1 = *(const float4*)&wf[(size_t)(m0 + am) * 256 + k0 + 16 + 4 * akq];
      Ag[4 * akq + 0][am] = a0.x; Ag[4 * akq + 1][am] = a0.y;
      Ag[4 * akq + 2][am] = a0.z; Ag[4 * akq + 3][am] = a0.w;
      Ag[16 + 4 * akq + 0][am] = a1.x; Ag[16 + 4 * akq + 1][am] = a1.y;
      Ag[16 + 4 * akq + 2][am] = a1.z; Ag[16 + 4 * akq + 3][am] = a1.w;
      float4 c0 = *(const float4*)&wf[(size_t)(256 + m0 + am) * 256 + k0 + 4 * akq];
      float4 c1 = *(const float4*)&wf[(size_t)(256 + m0 + am) * 256 + k0 + 16 + 4 * akq];
      Ab[4 * akq + 0][am] = c0.x; Ab[4 * akq + 1][am] = c0.y;
      Ab[4 * akq + 2][am] = c0.z; Ab[4 * akq + 3][am] = c0.w;
      Ab[16 + 4 * akq + 0][am] = c1.x; Ab[16 + 4 * akq + 1][am] = c1.y;
      Ab[16 + 4 * akq + 2][am] = c1.z; Ab[16 + 4 * akq + 3][am] = c1.w;
    }
#pragma unroll
    for (int p = 0; p < 4; ++p) {
      int idx = tid + p * 256;
      int t4 = idx & 31, k = idx >> 5;
      *(float4*)&Bs[k][4 * t4] = *(const float4*)&Y[(size_t)(k0 + k) * TTT + t0 + 4 * t4];
    }
    __syncthreads();
#pragma unroll
    for (int kk = 0; kk < 32; ++kk) {
      float4 ag = *(const float4*)&Ag[kk][4 * ty];
      float4 ab = *(const float4*)&Ab[kk][4 * ty];
      float4 bv0 = *(const float4*)&Bs[kk][4 * tx];
      float4 bv1 = *(const float4*)&Bs[kk][4 * tx + 64];
      const float g4[4] = {ag.x, ag.y, ag.z, ag.w};
      const float c4[4] = {ab.x, ab.y, ab.z, ab.w};
#pragma unroll
      for (int i = 0; i < 4; ++i) {
        accg[i][0] += g4[i] * bv0.x; accg[i][1] += g4[i] * bv0.y;
        accg[i][2] += g4[i] * bv0.z; accg[i][3] += g4[i] * bv0.w;
        accg[i][4] += g4[i] * bv1.x; accg[i][5] += g4[i] * bv1.y;
        accg[i][6] += g4[i] * bv1.z; accg[i][7] += g4[i] * bv1.w;
        accb[i][0] += c4[i] * bv0.x; accb[i][1] += c4[i] * bv0.y;
        accb[i][2] += c4[i] * bv0.z; accb[i][3] += c4[i] * bv0.w;
        accb[i][4] += c4[i] * bv1.x; accb[i][5] += c4[i] * bv1.y;
        accb[i][6] += c4[i] * bv1.z; accb[i][7] += c4[i] * bv1.w;
      }
    }
    __syncthreads();
  }

  const float* Xb = X + (size_t)b * CH * TTT;
  const float* xm = xmask + (size_t)b * TTT;
#pragma unroll
  for (int g = 0; g < 2; ++g) {
    int t = t0 + 4 * tx + 64 * g;
    float4 xmv = *(const float4*)&xm[t];
#pragma unroll
    for (int i = 0; i < 4; ++i) {
      int row = m0 + 4 * ty + i;
      float bg = bfilm[row], bb = bfilm[256 + row];
      float4 xv = *(const float4*)&Xb[(size_t)row * TTT + t];
      float4 ov;
      ov.x = (xv.x * (accg[i][4 * g + 0] + bg) + accb[i][4 * g + 0] + bb) * xmv.x;
      ov.y = (xv.y * (accg[i][4 * g + 1] + bg) + accb[i][4 * g + 1] + bb) * xmv.y;
      ov.z = (xv.z * (accg[i][4 * g + 2] + bg) + accb[i][4 * g + 2] + bb) * xmv.z;
      ov.w = (xv.w * (accg[i][4 * g + 3] + bg) + accb[i][4 * g + 3] + bb) * xmv.w;
      *(float4*)&out[((size_t)b * CH + row) * TTT + t] = ov;
    }
  }
}

// ---------------------------------------------------------------------------
extern "C" void kernel_launch(void* const* d_in, const int* in_sizes, int n_in,
                              void* d_out, int out_size, void* d_ws, size_t ws_size,
                              hipStream_t stream) {
  const float* x           = (const float*)d_in[0];
  const float* x_mask      = (const float*)d_in[1];
  const float* cond_latent = (const float*)d_in[2];
  const float* cond_mask   = (const float*)d_in[3];
  const float* w_cond      = (const float*)d_in[4];
  const float* b_cond      = (const float*)d_in[5];
  const float* wq          = (const float*)d_in[6];
  const float* bq          = (const float*)d_in[7];
  const float* wk          = (const float*)d_in[8];
  const float* bk          = (const float*)d_in[9];
  const float* wv          = (const float*)d_in[10];
  const float* bv          = (const float*)d_in[11];
  const float* wo          = (const float*)d_in[12];
  const float* bo          = (const float*)d_in[13];
  const float* w_film      = (const float*)d_in[14];
  const float* b_film      = (const float*)d_in[15];
  float* out = (float*)d_out;

  float* ws = (float*)d_ws;
  float* q_buf = ws;                    // 16*256*2048 = 8,388,608 (attn out in place)
  float* k_buf = q_buf + 8388608;       // 2,097,152
  float* v_buf = k_buf + 2097152;       // 2,097,152
  float* wk2   = v_buf + 2097152;       // 131,072
  float* wv2   = wk2 + 131072;          // 131,072
  float* wf2   = wv2 + 131072;          // 131,072
  float* bk2   = wf2 + 131072;          // 256
  float* bv2   = bk2 + 256;             // 256
  float* bf2   = bv2 + 256;             // 512
  float* zbuf  = bf2 + 512;             // 512 zeros

  dim3 blk(256);

  hipMemsetAsync(zbuf, 0, 512 * sizeof(float), stream);

  // --- weight folding (tiny GEMMs, B=1) ---
  gemm_v2<4, 2><<<dim3(8, 4, 1), blk, 0, stream>>>(
      wk, zbuf, wv, zbuf, w_cond, wk2, wv2, 256, 512);
  gemm_v2<4, 1><<<dim3(4, 8, 1), blk, 0, stream>>>(
      w_film, zbuf, nullptr, nullptr, wo, wf2, nullptr, 256, 256);
  bias_fold<<<dim3(4), blk, 0, stream>>>(wk, bk, wv, bv, b_cond,
                                         w_film, bo, b_film, bk2, bv2, bf2);

  // --- main pipeline ---
  gemm_v2<8, 1><<<dim3(16, 4, 16), blk, 0, stream>>>(
      wq, bq, nullptr, nullptr, x, q_buf, nullptr, 256, 2048);
  gemm_v2<4, 2><<<dim3(8, 4, 16), blk, 0, stream>>>(
      wk2, bk2, wv2, bv2, cond_latent, k_buf, v_buf, 512, 512);
  rope_kernel<<<4096, blk, 0, stream>>>(k_buf, 512, 9);
  attn_v5<<<dim3(32, 4, 16), dim3(128), 0, stream>>>(q_buf, k_buf, v_buf, cond_mask, q_buf);
  film_v2<<<dim3(16, 4, 16), blk, 0, stream>>>(wf2, bf2, q_buf, x, x_mask, out);
}

// Round 7
// 437.611 us; speedup vs baseline: 1.7276x; 1.7276x over previous
//
#include <hip/hip_runtime.h>
#include <math.h>

#define NB 16        // batch
#define CH 256       // hidden
#define NH 4
#define KC 64
#define TTT 2048
#define TSS 512

typedef __attribute__((ext_vector_type(8))) short bf16x8;
typedef __attribute__((ext_vector_type(4))) float f32x4;

__device__ inline short f2bf(float x) {   // round-to-nearest-even bf16
  unsigned u = __float_as_uint(x);
  u += 0x7fffu + ((u >> 16) & 1u);
  return (short)(u >> 16);
}
__device__ inline unsigned pack2bf(float a, float b) {
  return (unsigned)(unsigned short)f2bf(a) | ((unsigned)(unsigned short)f2bf(b) << 16);
}

// ---------------------------------------------------------------------------
// Templated tiled GEMM: Yn[b] = Wn @ X[b] + bn  (fp32, unchanged / passing)
// ---------------------------------------------------------------------------
template <int TN, int NOUT>
__global__ __launch_bounds__(256) void gemm_v2(
    const float* __restrict__ W0, const float* __restrict__ b0,
    const float* __restrict__ W1, const float* __restrict__ b1,
    const float* __restrict__ X, float* __restrict__ Y0, float* __restrict__ Y1,
    int K, int T) {
  constexpr int TT = 16 * TN;
  constexpr int TQ = TT / 4;
  constexpr int PB = (32 * TQ) / 256;
  const int t0 = blockIdx.x * TT;
  const int m0 = blockIdx.y * 64;
  const int b  = blockIdx.z;
  const int tid = threadIdx.x;
  const int tx = tid & 15, ty = tid >> 4;

  __shared__ float As[NOUT][32][68];
  __shared__ float Bs[32][TT + 4];

  const float* Xb = X + (size_t)b * K * T;
  float acc[NOUT][4][TN];
#pragma unroll
  for (int n = 0; n < NOUT; ++n)
#pragma unroll
    for (int i = 0; i < 4; ++i)
#pragma unroll
      for (int u = 0; u < TN; ++u) acc[n][i][u] = 0.f;

  const int am = tid >> 2, akq = tid & 3;

  for (int k0 = 0; k0 < K; k0 += 32) {
#pragma unroll
    for (int n = 0; n < NOUT; ++n) {
      const float* Wn = (n == 0) ? W0 : W1;
      float4 a0 = *(const float4*)&Wn[(size_t)(m0 + am) * K + k0 + 4 * akq];
      float4 a1 = *(const float4*)&Wn[(size_t)(m0 + am) * K + k0 + 16 + 4 * akq];
      As[n][4 * akq + 0][am] = a0.x; As[n][4 * akq + 1][am] = a0.y;
      As[n][4 * akq + 2][am] = a0.z; As[n][4 * akq + 3][am] = a0.w;
      As[n][16 + 4 * akq + 0][am] = a1.x; As[n][16 + 4 * akq + 1][am] = a1.y;
      As[n][16 + 4 * akq + 2][am] = a1.z; As[n][16 + 4 * akq + 3][am] = a1.w;
    }
#pragma unroll
    for (int p = 0; p < PB; ++p) {
      int idx = tid + p * 256;
      int t4 = idx & (TQ - 1), k = idx / TQ;
      *(float4*)&Bs[k][4 * t4] = *(const float4*)&Xb[(size_t)(k0 + k) * T + t0 + 4 * t4];
    }
    __syncthreads();
#pragma unroll
    for (int kk = 0; kk < 32; ++kk) {
      float4 av[NOUT];
#pragma unroll
      for (int n = 0; n < NOUT; ++n) av[n] = *(const float4*)&As[n][kk][4 * ty];
      float4 bv[TN / 4];
#pragma unroll
      for (int g = 0; g < TN / 4; ++g) bv[g] = *(const float4*)&Bs[kk][4 * tx + 64 * g];
#pragma unroll
      for (int n = 0; n < NOUT; ++n) {
        const float a4[4] = {av[n].x, av[n].y, av[n].z, av[n].w};
#pragma unroll
        for (int i = 0; i < 4; ++i)
#pragma unroll
          for (int g = 0; g < TN / 4; ++g) {
            acc[n][i][4 * g + 0] += a4[i] * bv[g].x;
            acc[n][i][4 * g + 1] += a4[i] * bv[g].y;
            acc[n][i][4 * g + 2] += a4[i] * bv[g].z;
            acc[n][i][4 * g + 3] += a4[i] * bv[g].w;
          }
      }
    }
    __syncthreads();
  }
#pragma unroll
  for (int n = 0; n < NOUT; ++n) {
    float* Yn = (n == 0) ? Y0 : Y1;
    const float* bn = (n == 0) ? b0 : b1;
#pragma unroll
    for (int i = 0; i < 4; ++i) {
      int row = m0 + 4 * ty + i;
      float bi = bn[row];
#pragma unroll
      for (int g = 0; g < TN / 4; ++g) {
        float4 ov;
        ov.x = acc[n][i][4 * g + 0] + bi; ov.y = acc[n][i][4 * g + 1] + bi;
        ov.z = acc[n][i][4 * g + 2] + bi; ov.w = acc[n][i][4 * g + 3] + bi;
        *(float4*)&Yn[((size_t)b * 256 + row) * T + t0 + 4 * tx + 64 * g] = ov;
      }
    }
  }
}

// ---------------------------------------------------------------------------
// Bias folding (unchanged / passing)
// ---------------------------------------------------------------------------
__global__ __launch_bounds__(256) void bias_fold(
    const float* __restrict__ wk, const float* __restrict__ bk,
    const float* __restrict__ wv, const float* __restrict__ bv,
    const float* __restrict__ bcond,
    const float* __restrict__ wfilm, const float* __restrict__ bo,
    const float* __restrict__ bfilm,
    float* __restrict__ bk2, float* __restrict__ bv2, float* __restrict__ bf2) {
  int g = blockIdx.x * 256 + threadIdx.x;
  if (g < 256) {
    float s = bk[g];
    for (int k = 0; k < 256; ++k) s += wk[g * 256 + k] * bcond[k];
    bk2[g] = s;
  } else if (g < 512) {
    int m = g - 256;
    float s = bv[m];
    for (int k = 0; k < 256; ++k) s += wv[m * 256 + k] * bcond[k];
    bv2[m] = s;
  } else if (g < 1024) {
    int m = g - 512;
    float s = bfilm[m];
    for (int k = 0; k < 256; ++k) s += wfilm[m * 256 + k] * bo[k];
    bf2[m] = s;
  }
}

// ---------------------------------------------------------------------------
// kvprep: K -> rope -> bf16 transposed [bh][s][64ch];  V -> bf16 [bh][64ch][s]
// Grid (TSS/64, NH, NB), block 256.
// ---------------------------------------------------------------------------
__global__ __launch_bounds__(256) void kvprep(
    const float* __restrict__ kf32, const float* __restrict__ vf32,
    short* __restrict__ kbf, short* __restrict__ vbf) {
  const int s0 = blockIdx.x * 64;
  const int h = blockIdx.y, b = blockIdx.z;
  const int bh = b * NH + h;
  const int tid = threadIdx.x;
  const float* kb = kf32 + ((size_t)(b * CH + h * KC)) * TSS;
  const float* vb = vf32 + ((size_t)(b * CH + h * KC)) * TSS;

  __shared__ float Kls[64 * 68];

  // stage K chunk with fused RoPE (pairs j, j+32)
#pragma unroll
  for (int p = 0; p < 2; ++p) {
    int idx = tid + p * 256;          // 0..511
    int j = idx >> 4, s4 = idx & 15;  // j 0..31
    float4 ka = *(const float4*)&kb[(size_t)j * TSS + s0 + 4 * s4];
    float4 kc = *(const float4*)&kb[(size_t)(j + 32) * TSS + s0 + 4 * s4];
    float invf = expf(-(float)j * 0.28782313662425572f);
    const float av[4] = {ka.x, ka.y, ka.z, ka.w};
    const float cv[4] = {kc.x, kc.y, kc.z, kc.w};
    float oa[4], oc[4];
#pragma unroll
    for (int e = 0; e < 4; ++e) {
      float ang = (float)(s0 + 4 * s4 + e) * invf;
      float cs = cosf(ang), sn = sinf(ang);
      oa[e] = av[e] * cs - cv[e] * sn;
      oc[e] = cv[e] * cs + av[e] * sn;
    }
    *(float4*)&Kls[j * 68 + 4 * s4] = make_float4(oa[0], oa[1], oa[2], oa[3]);
    *(float4*)&Kls[(j + 32) * 68 + 4 * s4] = make_float4(oc[0], oc[1], oc[2], oc[3]);
  }
  __syncthreads();

  // transpose K out: thread -> (s, 16-ch group)
  {
    int s = tid >> 2, g = tid & 3;
    unsigned ow[8];
#pragma unroll
    for (int hlf = 0; hlf < 8; ++hlf) {
      int ch = g * 16 + hlf * 2;
      ow[hlf] = pack2bf(Kls[ch * 68 + s], Kls[(ch + 1) * 68 + s]);
    }
    short* dst = kbf + ((size_t)bh * TSS + s0 + s) * 64 + g * 16;
    *(uint4*)dst = make_uint4(ow[0], ow[1], ow[2], ow[3]);
    *(uint4*)(dst + 8) = make_uint4(ow[4], ow[5], ow[6], ow[7]);
  }

  // V straight cvt
#pragma unroll
  for (int p = 0; p < 4; ++p) {
    int idx = tid + p * 256;          // 0..1023
    int ch = idx >> 4, s4 = idx & 15;
    float4 v = *(const float4*)&vb[(size_t)ch * TSS + s0 + 4 * s4];
    uint2 w2 = make_uint2(pack2bf(v.x, v.y), pack2bf(v.z, v.w));
    *(uint2*)(vbf + ((size_t)bh * KC + ch) * TSS + s0 + 4 * s4) = w2;
  }
}

// ---------------------------------------------------------------------------
// attn_mfma: bf16 MFMA attention. Block = (b, h, 64 t). 4 waves, each owns
// 16 t (m-dim). QK^T: D[t][s] = mfma(Qfrag, Kfrag) over k=ch (2 MFMAs);
// fp32 softmax (single-pass; masked cols -> 0); P (bf16) round-trips through
// per-wave-private LDS rows; PV: O[t][ch] = mfma(Pfrag, Vfrag). Layouts
// (m89/m120-verified): A [m=lane&15][k=quad*8+j]; B [n=lane&15][k=quad*8+j];
// C/D row=quad*4+reg, col=lane&15. All LDS 16B-block XOR-swizzled (<=2-way).
// LDS 50176 B -> 3 blocks/CU (12 waves).
// ---------------------------------------------------------------------------
__global__ __launch_bounds__(256, 3) void attn_mfma(
    const float* __restrict__ qbuf, const short* __restrict__ kbf,
    const short* __restrict__ vbf, const float* __restrict__ cond_mask,
    float* __restrict__ obuf) {
  const int t0 = blockIdx.x * 64;
  const int h = blockIdx.y, b = blockIdx.z;
  const int bh = b * NH + h;
  const int tid = threadIdx.x;
  const int w = tid >> 6, lane = tid & 63;
  const int quad = lane >> 4, l15 = lane & 15;

  __shared__ __align__(16) char smem[50176];
  short* Ks = (short*)smem;                 // [s*64 + 8*((ch>>3)^(s&7)) + (ch&7)]   128x64
  short* Vs = (short*)(smem + 16384);       // [ch*128 + 8*((s>>3)^(ch&7)) + (s&7)]  64x128
  float* Qf = (float*)(smem + 32768);       // [ch*68 + t]  64x68 fp32 (Q stage / O stage)
  short* Ps = (short*)(smem + 32768);       // [t*128 + 8*((s>>3)^(t&7)) + (s&7)]    64x128

  // ---- stage Q fp32 with fused RoPE ----
  const float* qb = qbuf + ((size_t)(b * CH + h * KC)) * TTT + t0;
#pragma unroll
  for (int p = 0; p < 2; ++p) {
    int idx = tid + p * 256;          // 0..511
    int j = idx >> 4, t4 = idx & 15;  // j 0..31
    float4 qa = *(const float4*)&qb[(size_t)j * TTT + 4 * t4];
    float4 qc = *(const float4*)&qb[(size_t)(j + 32) * TTT + 4 * t4];
    float invf = expf(-(float)j * 0.28782313662425572f);
    const float av[4] = {qa.x, qa.y, qa.z, qa.w};
    const float cv[4] = {qc.x, qc.y, qc.z, qc.w};
    float oa[4], oc[4];
#pragma unroll
    for (int e = 0; e < 4; ++e) {
      float ang = (float)(t0 + 4 * t4 + e) * invf;
      float cs = cosf(ang), sn = sinf(ang);
      oa[e] = av[e] * cs - cv[e] * sn;
      oc[e] = cv[e] * cs + av[e] * sn;
    }
    *(float4*)&Qf[j * 68 + 4 * t4] = make_float4(oa[0], oa[1], oa[2], oa[3]);
    *(float4*)&Qf[(j + 32) * 68 + 4 * t4] = make_float4(oc[0], oc[1], oc[2], oc[3]);
  }
  __syncthreads();

  // ---- gather Q A-frags into registers (bf16) ----
  const int tcol = w * 16 + l15;
  bf16x8 qf0, qf1;
#pragma unroll
  for (int j = 0; j < 8; ++j) {
    qf0[j] = f2bf(Qf[(quad * 8 + j) * 68 + tcol]);
    qf1[j] = f2bf(Qf[(32 + quad * 8 + j) * 68 + tcol]);
  }

  f32x4 acc_o[4];
#pragma unroll
  for (int n = 0; n < 4; ++n) acc_o[n] = (f32x4){0.f, 0.f, 0.f, 0.f};
  float den[4] = {0.f, 0.f, 0.f, 0.f};

  const float* cm = cond_mask + (size_t)b * TSS;
  const short* kbase = kbf + (size_t)bh * TSS * 64;
  const short* vbase = vbf + (size_t)bh * KC * TSS;

  for (int s0 = 0; s0 < TSS; s0 += 128) {
    __syncthreads();   // (A) prior tile's K/V frag reads complete
    // ---- stage K, V (bf16, swizzled) ----
#pragma unroll
    for (int p = 0; p < 4; ++p) {
      int idx = tid + p * 256;          // 0..1023
      int blk = idx & 7, sr = idx >> 3; // sr 0..127
      *(uint4*)&Ks[sr * 64 + 8 * (blk ^ (sr & 7))] =
          *(const uint4*)&kbase[(size_t)(s0 + sr) * 64 + 8 * blk];
    }
#pragma unroll
    for (int p = 0; p < 4; ++p) {
      int idx = tid + p * 256;          // 0..1023
      int blk = idx & 15, ch = idx >> 4;
      *(uint4*)&Vs[ch * 128 + 8 * (blk ^ (ch & 7))] =
          *(const uint4*)&vbase[(size_t)ch * TSS + s0 + 8 * blk];
    }
    __syncthreads();   // (B) staging visible

    // ---- QK^T + softmax + P write (P rows are per-wave private) ----
#pragma unroll
    for (int n0 = 0; n0 < 8; ++n0) {
      int srow = n0 * 16 + l15;
      bf16x8 kf0 = *(const bf16x8*)&Ks[srow * 64 + 8 * (quad ^ (srow & 7))];
      bf16x8 kf1 = *(const bf16x8*)&Ks[srow * 64 + 8 * ((4 + quad) ^ (srow & 7))];
      f32x4 acc = (f32x4){0.f, 0.f, 0.f, 0.f};
      acc = __builtin_amdgcn_mfma_f32_16x16x32_bf16(qf0, kf0, acc, 0, 0, 0);
      acc = __builtin_amdgcn_mfma_f32_16x16x32_bf16(qf1, kf1, acc, 0, 0, 0);
      float mk = (cm[s0 + srow] != 0.f) ? 1.f : 0.f;
      int sblk = n0 * 2 + (l15 >> 3);
      int slow = l15 & 7;
#pragma unroll
      for (int r = 0; r < 4; ++r) {
        float e = __expf(acc[r] * 0.125f) * mk;
        den[r] += e;
        int trow = w * 16 + quad * 4 + r;
        Ps[trow * 128 + 8 * (sblk ^ (trow & 7)) + slow] = f2bf(e);
      }
    }

    // ---- PV: O += P V ----
    {
      int trow = w * 16 + l15;
#pragma unroll
      for (int kt = 0; kt < 4; ++kt) {
        bf16x8 pf = *(const bf16x8*)&Ps[trow * 128 + 8 * ((kt * 4 + quad) ^ (trow & 7))];
#pragma unroll
        for (int n0 = 0; n0 < 4; ++n0) {
          int ch = n0 * 16 + l15;
          bf16x8 vf = *(const bf16x8*)&Vs[ch * 128 + 8 * ((kt * 4 + quad) ^ (ch & 7))];
          acc_o[n0] = __builtin_amdgcn_mfma_f32_16x16x32_bf16(pf, vf, acc_o[n0], 0, 0, 0);
        }
      }
    }
  }

  // ---- denominators: reduce over the 16 s-lanes within each quad ----
  float rd[4];
#pragma unroll
  for (int r = 0; r < 4; ++r) {
    float d = den[r];
#pragma unroll
    for (int off = 1; off < 16; off <<= 1) d += __shfl_xor(d, off, 16);
    rd[r] = 1.f / fmaxf(d, 1e-30f);
  }

  __syncthreads();   // all PV reads done; reuse Qf region as O [ch][t]
#pragma unroll
  for (int n0 = 0; n0 < 4; ++n0)
#pragma unroll
    for (int r = 0; r < 4; ++r) {
      int ch = n0 * 16 + l15;
      int trow = w * 16 + quad * 4 + r;
      Qf[ch * 68 + trow] = acc_o[n0][r] * rd[r];
    }
  __syncthreads();

  float* ob = obuf + ((size_t)(b * CH + h * KC)) * TTT + t0;
#pragma unroll
  for (int p = 0; p < 4; ++p) {
    int idx = tid + p * 256;
    int ch = idx >> 4, t4 = idx & 15;
    *(float4*)&ob[(size_t)ch * TTT + 4 * t4] = *(const float4*)&Qf[ch * 68 + 4 * t4];
  }
}

// ---------------------------------------------------------------------------
// Film (unchanged / passing): gb = wf2 @ ao + bf2; out = (x*gamma+beta)*mask
// ---------------------------------------------------------------------------
__global__ __launch_bounds__(256) void film_v2(
    const float* __restrict__ wf, const float* __restrict__ bfilm,
    const float* __restrict__ Yb, const float* __restrict__ X,
    const float* __restrict__ xmask, float* __restrict__ out) {
  const int t0 = blockIdx.x * 128;
  const int m0 = blockIdx.y * 64;
  const int b  = blockIdx.z;
  const int tid = threadIdx.x;
  const int tx = tid & 15, ty = tid >> 4;

  __shared__ float Ag[32][68];
  __shared__ float Ab[32][68];
  __shared__ float Bs[32][132];

  const float* Y = Yb + (size_t)b * CH * TTT;
  float accg[4][8], accb[4][8];
#pragma unroll
  for (int i = 0; i < 4; ++i)
#pragma unroll
    for (int u = 0; u < 8; ++u) { accg[i][u] = 0.f; accb[i][u] = 0.f; }

  const int am = tid >> 2, akq = tid & 3;

  for (int k0 = 0; k0 < 256; k0 += 32) {
    {
      float4 a0 = *(const float4*)&wf[(size_t)(m0 + am) * 256 + k0 + 4 * akq];
      float4 a1 = *(const float4*)&wf[(size_t)(m0 + am) * 256 + k0 + 16 + 4 * akq];
      Ag[4 * akq + 0][am] = a0.x; Ag[4 * akq + 1][am] = a0.y;
      Ag[4 * akq + 2][am] = a0.z; Ag[4 * akq + 3][am] = a0.w;
      Ag[16 + 4 * akq + 0][am] = a1.x; Ag[16 + 4 * akq + 1][am] = a1.y;
      Ag[16 + 4 * akq + 2][am] = a1.z; Ag[16 + 4 * akq + 3][am] = a1.w;
      float4 c0 = *(const float4*)&wf[(size_t)(256 + m0 + am) * 256 + k0 + 4 * akq];
      float4 c1 = *(const float4*)&wf[(size_t)(256 + m0 + am) * 256 + k0 + 16 + 4 * akq];
      Ab[4 * akq + 0][am] = c0.x; Ab[4 * akq + 1][am] = c0.y;
      Ab[4 * akq + 2][am] = c0.z; Ab[4 * akq + 3][am] = c0.w;
      Ab[16 + 4 * akq + 0][am] = c1.x; Ab[16 + 4 * akq + 1][am] = c1.y;
      Ab[16 + 4 * akq + 2][am] = c1.z; Ab[16 + 4 * akq + 3][am] = c1.w;
    }
#pragma unroll
    for (int p = 0; p < 4; ++p) {
      int idx = tid + p * 256;
      int t4 = idx & 31, k = idx >> 5;
      *(float4*)&Bs[k][4 * t4] = *(const float4*)&Y[(size_t)(k0 + k) * TTT + t0 + 4 * t4];
    }
    __syncthreads();
#pragma unroll
    for (int kk = 0; kk < 32; ++kk) {
      float4 ag = *(const float4*)&Ag[kk][4 * ty];
      float4 ab = *(const float4*)&Ab[kk][4 * ty];
      float4 bv0 = *(const float4*)&Bs[kk][4 * tx];
      float4 bv1 = *(const float4*)&Bs[kk][4 * tx + 64];
      const float g4[4] = {ag.x, ag.y, ag.z, ag.w};
      const float c4[4] = {ab.x, ab.y, ab.z, ab.w};
#pragma unroll
      for (int i = 0; i < 4; ++i) {
        accg[i][0] += g4[i] * bv0.x; accg[i][1] += g4[i] * bv0.y;
        accg[i][2] += g4[i] * bv0.z; accg[i][3] += g4[i] * bv0.w;
        accg[i][4] += g4[i] * bv1.x; accg[i][5] += g4[i] * bv1.y;
        accg[i][6] += g4[i] * bv1.z; accg[i][7] += g4[i] * bv1.w;
        accb[i][0] += c4[i] * bv0.x; accb[i][1] += c4[i] * bv0.y;
        accb[i][2] += c4[i] * bv0.z; accb[i][3] += c4[i] * bv0.w;
        accb[i][4] += c4[i] * bv1.x; accb[i][5] += c4[i] * bv1.y;
        accb[i][6] += c4[i] * bv1.z; accb[i][7] += c4[i] * bv1.w;
      }
    }
    __syncthreads();
  }

  const float* Xb = X + (size_t)b * CH * TTT;
  const float* xm = xmask + (size_t)b * TTT;
#pragma unroll
  for (int g = 0; g < 2; ++g) {
    int t = t0 + 4 * tx + 64 * g;
    float4 xmv = *(const float4*)&xm[t];
#pragma unroll
    for (int i = 0; i < 4; ++i) {
      int row = m0 + 4 * ty + i;
      float bg = bfilm[row], bb = bfilm[256 + row];
      float4 xv = *(const float4*)&Xb[(size_t)row * TTT + t];
      float4 ov;
      ov.x = (xv.x * (accg[i][4 * g + 0] + bg) + accb[i][4 * g + 0] + bb) * xmv.x;
      ov.y = (xv.y * (accg[i][4 * g + 1] + bg) + accb[i][4 * g + 1] + bb) * xmv.y;
      ov.z = (xv.z * (accg[i][4 * g + 2] + bg) + accb[i][4 * g + 2] + bb) * xmv.z;
      ov.w = (xv.w * (accg[i][4 * g + 3] + bg) + accb[i][4 * g + 3] + bb) * xmv.w;
      *(float4*)&out[((size_t)b * CH + row) * TTT + t] = ov;
    }
  }
}

// ---------------------------------------------------------------------------
extern "C" void kernel_launch(void* const* d_in, const int* in_sizes, int n_in,
                              void* d_out, int out_size, void* d_ws, size_t ws_size,
                              hipStream_t stream) {
  const float* x           = (const float*)d_in[0];
  const float* x_mask      = (const float*)d_in[1];
  const float* cond_latent = (const float*)d_in[2];
  const float* cond_mask   = (const float*)d_in[3];
  const float* w_cond      = (const float*)d_in[4];
  const float* b_cond      = (const float*)d_in[5];
  const float* wq          = (const float*)d_in[6];
  const float* bq          = (const float*)d_in[7];
  const float* wk          = (const float*)d_in[8];
  const float* bk          = (const float*)d_in[9];
  const float* wv          = (const float*)d_in[10];
  const float* bv          = (const float*)d_in[11];
  const float* wo          = (const float*)d_in[12];
  const float* bo          = (const float*)d_in[13];
  const float* w_film      = (const float*)d_in[14];
  const float* b_film      = (const float*)d_in[15];
  float* out = (float*)d_out;

  float* ws = (float*)d_ws;
  float* q_buf = ws;                    // 16*256*2048 (attn out in place)
  float* k_buf = q_buf + 8388608;       // 2,097,152
  float* v_buf = k_buf + 2097152;       // 2,097,152
  float* wk2   = v_buf + 2097152;       // 131,072
  float* wv2   = wk2 + 131072;          // 131,072
  float* wf2   = wv2 + 131072;          // 131,072
  float* bk2   = wf2 + 131072;          // 256
  float* bv2   = bk2 + 256;             // 256
  float* bf2   = bv2 + 256;             // 512
  float* zbuf  = bf2 + 512;             // 512 zeros
  short* k_bf  = (short*)(zbuf + 512);  // 16*4*512*64 bf16
  short* v_bf  = k_bf + 2097152;        // 16*4*64*512 bf16

  dim3 blk(256);

  hipMemsetAsync(zbuf, 0, 512 * sizeof(float), stream);

  // --- weight folding (tiny GEMMs, B=1) ---
  gemm_v2<4, 2><<<dim3(8, 4, 1), blk, 0, stream>>>(
      wk, zbuf, wv, zbuf, w_cond, wk2, wv2, 256, 512);
  gemm_v2<4, 1><<<dim3(4, 8, 1), blk, 0, stream>>>(
      w_film, zbuf, nullptr, nullptr, wo, wf2, nullptr, 256, 256);
  bias_fold<<<dim3(4), blk, 0, stream>>>(wk, bk, wv, bv, b_cond,
                                         w_film, bo, b_film, bk2, bv2, bf2);

  // --- main pipeline ---
  gemm_v2<8, 1><<<dim3(16, 4, 16), blk, 0, stream>>>(
      wq, bq, nullptr, nullptr, x, q_buf, nullptr, 256, 2048);
  gemm_v2<4, 2><<<dim3(8, 4, 16), blk, 0, stream>>>(
      wk2, bk2, wv2, bv2, cond_latent, k_buf, v_buf, 512, 512);
  // K rope + transpose + bf16; V bf16
  kvprep<<<dim3(8, 4, 16), blk, 0, stream>>>(k_buf, v_buf, k_bf, v_bf);
  // MFMA attention (in-place over q_buf)
  attn_mfma<<<dim3(32, 4, 16), blk, 0, stream>>>(q_buf, k_bf, v_bf, cond_mask, q_buf);
  // film + final output
  film_v2<<<dim3(16, 4, 16), blk, 0, stream>>>(wf2, bf2, q_buf, x, x_mask, out);
}